// Round 7
// baseline (243.903 us; speedup 1.0000x reference)
//
#include <hip/hip_runtime.h>

// AdaptiveSoftmax on MI355X — round 7.
// R6 post-mortem: cooperative launch silently failed (grid 1280 > max
// co-resident for 32KB-LDS kernel; R3/R5 occupancy says ~2.75 blocks/CU).
// Reverted to R5 skeleton. R7 = algorithmic cut: tail denominators are only
// needed for rows whose target is in that cluster (ref: where(mask,g,0)).
//   prep: classify rows -> idx0/idx1 (compaction), pos0/pos1 (inverse), cnts
//   hgemm: h0/h1 only for compacted rows (gathered A), compact-ordered out
//   tails: compact rows (no gather in hot loop), scatter via idx at the end
//   combine: fused loss via atomicAdd + ticket (drops k_loss dispatch)
// tail0 work -84%, tail1 -20%, hgemm -70%, one fewer dispatch.

typedef __attribute__((ext_vector_type(8))) short short8;
typedef __attribute__((ext_vector_type(4))) float f32x4;

#define LOG2E 1.4426950408889634f
#define LN2   0.6931471805599453f

__device__ __forceinline__ float b2f(unsigned short u){
    return __uint_as_float(((unsigned int)u) << 16);
}
__device__ __forceinline__ unsigned short f2b(float f){
    unsigned int x = __float_as_uint(f);
    x += 0x7fffu + ((x >> 16) & 1u);
    return (unsigned short)(x >> 16);
}
__device__ __forceinline__ float dotu(unsigned int xu, unsigned int wu){
    float a = __uint_as_float(xu << 16) * __uint_as_float(wu << 16);
    float b = __uint_as_float(xu & 0xffff0000u) * __uint_as_float(wu & 0xffff0000u);
    return a + b;
}
__device__ __forceinline__ float fexp2(float x){
#if __has_builtin(__builtin_amdgcn_exp2f)
    return __builtin_amdgcn_exp2f(x);
#else
    float r; asm("v_exp_f32 %0, %1" : "=v"(r) : "v"(x)); return r;
#endif
}
__device__ __forceinline__ void gload16(const unsigned short* g, unsigned short* l){
    __builtin_amdgcn_global_load_lds(
        (const __attribute__((address_space(1))) unsigned int*)g,
        (__attribute__((address_space(3))) unsigned int*)l, 16, 0, 0);
}

// ---------------- prep: converts + transposes + row classification ----------
__global__ __launch_bounds__(256) void k_prep(
    const float* __restrict__ X, const float* __restrict__ headW,
    const float* __restrict__ emb0, const float* __restrict__ emb1,
    const float* __restrict__ lin0, const float* __restrict__ lin1,
    const int* __restrict__ tgt,
    unsigned short* __restrict__ Xb, unsigned short* __restrict__ hWb,
    unsigned short* __restrict__ e0b, unsigned short* __restrict__ e1b,
    unsigned short* __restrict__ l0T, unsigned short* __restrict__ l1T,
    int* __restrict__ idx0, int* __restrict__ idx1,
    int* __restrict__ pos0, int* __restrict__ pos1, int* __restrict__ cnt)
{
    __shared__ unsigned short tileT[64][65];
    const int b = blockIdx.x, t = threadIdx.x;
    if (b < 80){
        const float* src; unsigned short* dst; int C, tx, ty;
        if (b < 64){ src = lin0; dst = l0T; C = 256; tx = b & 3; ty = b >> 2; }
        else       { src = lin1; dst = l1T; C = 64;  tx = 0;     ty = b - 64; }
        #pragma unroll
        for (int e = 0; e < 16; ++e){
            int idx = t + e*256, r = idx >> 6, c = idx & 63;
            tileT[c][r] = f2b(src[(ty*64 + r)*C + tx*64 + c]);
        }
        __syncthreads();
        #pragma unroll
        for (int e = 0; e < 16; ++e){
            int idx = t + e*256, cc = idx >> 6, rr = idx & 63;
            dst[(tx*64 + cc)*1024 + ty*64 + rr] = tileT[cc][rr];
        }
        return;
    }
    const int NX = 1048576, NH = 512512, NE0 = 512000, NE1 = 644112;
    const int NV = NX + NH + NE0 + NE1;
    const int total = NV + 4096;           // + row classification
    int stride = (gridDim.x - 80) * 256;
    for (int i = (b - 80)*256 + t; i < total; i += stride){
        if (i < NV){
            const float* src; unsigned short* dst; int off; float sc;
            if (i < NX)            { src = X;     dst = Xb;  off = i;           sc = 1.0f;  }
            else if (i < NX+NH)    { src = headW; dst = hWb; off = i-NX;        sc = LOG2E; }
            else if (i < NX+NH+NE0){ src = emb0;  dst = e0b; off = i-NX-NH;     sc = LOG2E; }
            else                   { src = emb1;  dst = e1b; off = i-NX-NH-NE0; sc = LOG2E; }
            float4 v = ((const float4*)src)[off];
            ushort4 o;
            o.x = f2b(v.x*sc); o.y = f2b(v.y*sc);
            o.z = f2b(v.z*sc); o.w = f2b(v.w*sc);
            ((ushort4*)dst)[off] = o;
        } else {
            int row = i - NV;
            int tv = tgt[row];
            int p0 = 0, p1 = 0;
            if (tv >= 2000 && tv < 10000){
                int p = atomicAdd(&cnt[0], 1); idx0[p] = row; p0 = p;
            } else if (tv >= 10000){
                int p = atomicAdd(&cnt[1], 1); idx1[p] = row; p1 = p;
            }
            pos0[row] = p0; pos1[row] = p1;
        }
    }
}

// ------- h-GEMM (K=1024) for compacted rows, compact-ordered output ---------
// 320 blocks: j<256 -> h0 (band=j>>2 of 64 gathered rows, cb=j&3 of 4),
//             j>=256 -> h1 (band=j-256, 64 cols). Early-exit beyond counts.
__global__ __launch_bounds__(256) void k_hgemm(
    const unsigned short* __restrict__ A,    // Xb [4096][1024]
    const unsigned short* __restrict__ B0, unsigned short* __restrict__ C0,
    const unsigned short* __restrict__ B1, unsigned short* __restrict__ C1,
    const int* __restrict__ idx0, const int* __restrict__ idx1,
    const int* __restrict__ cnt)
{
    constexpr int K = 1024;
    __shared__ __align__(16) unsigned short As[64*64];
    __shared__ __align__(16) unsigned short Bs[64*64];

    const int j = blockIdx.x;
    const bool isH0 = (j < 256);
    const int band = isH0 ? (j >> 2) : (j - 256);
    const int cntv = isH0 ? cnt[0] : cnt[1];
    if (band >= ((cntv + 63) >> 6)) return;
    const unsigned short* B = isH0 ? B0 : B1;
    unsigned short* C = isH0 ? C0 : C1;
    const int M  = isH0 ? 256 : 64;
    const int cb = isH0 ? (j & 3) : 0;
    const int* idx = isH0 ? idx0 : idx1;

    const int tid  = threadIdx.x;
    const int lane = tid & 63;
    const int w    = tid >> 6;
    const int waveR = w >> 1, waveC = w & 1;
    const int quad  = lane >> 4, l16 = lane & 15;

    // gathered staging rows (fixed per thread across the K loop)
    const int r0l = tid >> 3, r1l = r0l + 32, g = tid & 7;
    const int gr0 = idx[min(band*64 + r0l, cntv - 1)];
    const int gr1 = idx[min(band*64 + r1l, cntv - 1)];

    f32x4 acc[2][2];
    #pragma unroll
    for (int i = 0; i < 2; ++i)
    #pragma unroll
    for (int jj = 0; jj < 2; ++jj) acc[i][jj] = (f32x4){0.f,0.f,0.f,0.f};

    for (int kc = 0; kc < K/64; ++kc){
        __syncthreads();
        *((uint4*)&As[r0l*64 + ((g ^ (r0l & 7)) << 3)]) =
            *(const uint4*)(A + (size_t)gr0*K + kc*64 + g*8);
        *((uint4*)&As[r1l*64 + ((g ^ (r1l & 7)) << 3)]) =
            *(const uint4*)(A + (size_t)gr1*K + kc*64 + g*8);
        *((uint4*)&Bs[r0l*64 + ((g ^ (r0l & 7)) << 3)]) =
            *(const uint4*)(B + (size_t)(cb*64 + r0l)*K + kc*64 + g*8);
        *((uint4*)&Bs[r1l*64 + ((g ^ (r1l & 7)) << 3)]) =
            *(const uint4*)(B + (size_t)(cb*64 + r1l)*K + kc*64 + g*8);
        __syncthreads();
        #pragma unroll
        for (int ks = 0; ks < 2; ++ks){
            short8 a[2], bb[2];
            #pragma unroll
            for (int i = 0; i < 2; ++i){
                int r = waveR*32 + i*16 + l16;
                int gg = ks*4 + quad;
                a[i] = *(const short8*)&As[r*64 + ((gg ^ (r & 7)) << 3)];
            }
            #pragma unroll
            for (int jj = 0; jj < 2; ++jj){
                int r = waveC*32 + jj*16 + l16;
                int gg = ks*4 + quad;
                bb[jj] = *(const short8*)&Bs[r*64 + ((gg ^ (r & 7)) << 3)];
            }
            #pragma unroll
            for (int i = 0; i < 2; ++i)
            #pragma unroll
            for (int jj = 0; jj < 2; ++jj)
                acc[i][jj] = __builtin_amdgcn_mfma_f32_16x16x32_bf16(
                    a[i], bb[jj], acc[i][jj], 0, 0, 0);
        }
    }
    #pragma unroll
    for (int i = 0; i < 2; ++i)
    #pragma unroll
    for (int jj = 0; jj < 2; ++jj)
    #pragma unroll
    for (int r = 0; r < 4; ++r){
        int crow = band*64 + waveR*32 + i*16 + quad*4 + r;   // compact row
        int col  = cb*64 + waveC*32 + jj*16 + l16;
        C[crow*M + col] = f2b(acc[i][jj][r]);
    }
}

// ------------- LDS GEMM+sumexp: 64x64 dbuf, global_load_lds staging ---------
// idx==nullptr: direct rows (head). idx!=nullptr: A holds compact rows;
// scatter via idx with bound cnt.
template<int K>
__device__ __forceinline__ void sumexp_lds(
    const unsigned short* __restrict__ A,
    const unsigned short* __restrict__ B,
    float* __restrict__ s_out, int M,
    int rowb, int cb0, int cb1,
    unsigned short* __restrict__ As, unsigned short* __restrict__ Bs,
    const int* __restrict__ idx, int cnt)
{
    constexpr int KCH = K / 64;
    constexpr int LK  = (KCH == 16) ? 4 : 2;
    static_assert(KCH == 16 || KCH == 4, "");
    const int tid  = threadIdx.x;
    const int lane = tid & 63, w = tid >> 6;
    const int waveR = w >> 1, waveC = w & 1;
    const int quad  = lane >> 4, l16 = lane & 15;
    const int row0  = rowb * 64;
    const int nit   = (cb1 - cb0) << LK;

    float s_loc[8];
    #pragma unroll
    for (int i = 0; i < 8; ++i) s_loc[i] = 0.f;
    f32x4 acc[2][2];
    #pragma unroll
    for (int i = 0; i < 2; ++i)
    #pragma unroll
    for (int j = 0; j < 2; ++j) acc[i][j] = (f32x4){0.f,0.f,0.f,0.f};

    const int sr = w*16 + (lane >> 3);
    const int gk = ((lane & 7) ^ (sr & 7)) << 3;

    int aoff[2][2], boff[2][2];
    #pragma unroll
    for (int x = 0; x < 2; ++x)
    #pragma unroll
    for (int ks = 0; ks < 2; ++ks){
        int ra = waveR*32 + x*16 + l16;
        int rb = waveC*32 + x*16 + l16;
        int g  = ks*4 + quad;
        aoff[x][ks] = ra*64 + ((g ^ (ra & 7)) << 3);
        boff[x][ks] = rb*64 + ((g ^ (rb & 7)) << 3);
    }

    auto stage = [&](int it){
        int cb = cb0 + (it >> LK);
        int kc = it & (KCH - 1);
        unsigned short* Ad = As + (it & 1)*4096 + w*1024;
        unsigned short* Bd = Bs + (it & 1)*4096 + w*1024;
        const unsigned short* ga = A + (size_t)(row0 + sr)*K + kc*64 + gk;
        gload16(ga,        Ad);
        gload16(ga + 8*K,  Ad + 512);
        int br0 = cb*64 + sr;     if (br0 > M-1) br0 = M-1;
        int br1 = cb*64 + sr + 8; if (br1 > M-1) br1 = M-1;
        gload16(B + (size_t)br0*K + kc*64 + gk, Bd);
        gload16(B + (size_t)br1*K + kc*64 + gk, Bd + 512);
    };

    stage(0);
    __syncthreads();

    for (int it = 0; it < nit; ++it){
        if (it + 1 < nit) stage(it + 1);
        const unsigned short* Ac = As + (it & 1)*4096;
        const unsigned short* Bc = Bs + (it & 1)*4096;
        #pragma unroll
        for (int ks = 0; ks < 2; ++ks){
            short8 a0 = *(const short8*)(Ac + aoff[0][ks]);
            short8 a1 = *(const short8*)(Ac + aoff[1][ks]);
            short8 b0 = *(const short8*)(Bc + boff[0][ks]);
            short8 b1 = *(const short8*)(Bc + boff[1][ks]);
            acc[0][0] = __builtin_amdgcn_mfma_f32_16x16x32_bf16(a0, b0, acc[0][0], 0,0,0);
            acc[0][1] = __builtin_amdgcn_mfma_f32_16x16x32_bf16(a0, b1, acc[0][1], 0,0,0);
            acc[1][0] = __builtin_amdgcn_mfma_f32_16x16x32_bf16(a1, b0, acc[1][0], 0,0,0);
            acc[1][1] = __builtin_amdgcn_mfma_f32_16x16x32_bf16(a1, b1, acc[1][1], 0,0,0);
        }
        if ((it & (KCH - 1)) == (KCH - 1)){
            int cb = cb0 + (it >> LK);
            if ((cb + 1)*64 <= M){
                #pragma unroll
                for (int i = 0; i < 2; ++i)
                #pragma unroll
                for (int j = 0; j < 2; ++j)
                #pragma unroll
                for (int r = 0; r < 4; ++r)
                    s_loc[i*4 + r] += fexp2(acc[i][j][r]);
            } else {
                #pragma unroll
                for (int j = 0; j < 2; ++j){
                    int col = cb*64 + waveC*32 + j*16 + l16;
                    if (col < M){
                        #pragma unroll
                        for (int i = 0; i < 2; ++i)
                        #pragma unroll
                        for (int r = 0; r < 4; ++r)
                            s_loc[i*4 + r] += fexp2(acc[i][j][r]);
                    }
                }
            }
            #pragma unroll
            for (int i = 0; i < 2; ++i)
            #pragma unroll
            for (int j = 0; j < 2; ++j) acc[i][j] = (f32x4){0.f,0.f,0.f,0.f};
        }
        __syncthreads();
    }

    #pragma unroll
    for (int k = 0; k < 8; ++k){
        #pragma unroll
        for (int m = 1; m < 16; m <<= 1)
            s_loc[k] += __shfl_xor(s_loc[k], m, 64);
    }
    if (l16 < 8){
        int i = l16 >> 2, r = l16 & 3;
        int lrow = row0 + waveR*32 + i*16 + quad*4 + r;
        if (idx){
            if (lrow < cnt) atomicAdd(&s_out[idx[lrow]], s_loc[l16]);
        } else {
            atomicAdd(&s_out[lrow], s_loc[l16]);
        }
    }
}

// ------------- tail1 (K=64): barrier-free streaming over compact rows -------
__device__ __forceinline__ void sumexp_stream64(
    const unsigned short* __restrict__ A,   // h1b compact [*][64]
    const unsigned short* __restrict__ B,   // e1b [40257][64] (scaled)
    float* __restrict__ s_out, int row0, int g0, int g1,
    const int* __restrict__ idx, int cnt)
{
    const int M = 40257;
    const int lane = threadIdx.x & 63;
    const int quad = lane >> 4, l16 = lane & 15;

    short8 a[4][2];
    #pragma unroll
    for (int i = 0; i < 4; ++i)
    #pragma unroll
    for (int ks = 0; ks < 2; ++ks)
        a[i][ks] = *(const short8*)(A + (size_t)(row0 + i*16 + l16)*64 + ks*32 + quad*8);

    f32x4 sums[4];
    #pragma unroll
    for (int i = 0; i < 4; ++i) sums[i] = (f32x4){0.f,0.f,0.f,0.f};

    short8 p0a, p1a, p0b, p1b;
    auto loadB = [&](int g, short8& d0, short8& d1){
        int n = g*16 + l16; if (n > M-1) n = M-1;
        const unsigned short* p = B + (size_t)n*64 + quad*8;
        d0 = *(const short8*)p;
        d1 = *(const short8*)(p + 32);
    };
    auto body = [&](int g, short8 b0, short8 b1){
        f32x4 acc[4];
        #pragma unroll
        for (int i = 0; i < 4; ++i) acc[i] = (f32x4){0.f,0.f,0.f,0.f};
        #pragma unroll
        for (int i = 0; i < 4; ++i)
            acc[i] = __builtin_amdgcn_mfma_f32_16x16x32_bf16(a[i][0], b0, acc[i], 0,0,0);
        #pragma unroll
        for (int i = 0; i < 4; ++i)
            acc[i] = __builtin_amdgcn_mfma_f32_16x16x32_bf16(a[i][1], b1, acc[i], 0,0,0);
        if (g*16 + l16 < M){
            #pragma unroll
            for (int i = 0; i < 4; ++i){
                sums[i][0] += fexp2(acc[i][0]);
                sums[i][1] += fexp2(acc[i][1]);
                sums[i][2] += fexp2(acc[i][2]);
                sums[i][3] += fexp2(acc[i][3]);
            }
        }
    };

    loadB(g0, p0a, p1a);
    loadB(g0 + 1, p0b, p1b);
    for (int g = g0; g < g1; g += 2){
        body(g, p0a, p1a);
        if (g + 2 < g1) loadB(g + 2, p0a, p1a);
        if (g + 1 < g1){
            body(g + 1, p0b, p1b);
            if (g + 3 < g1) loadB(g + 3, p0b, p1b);
        }
    }

    #pragma unroll
    for (int i = 0; i < 4; ++i){
        #pragma unroll
        for (int r = 0; r < 4; ++r){
            float v = sums[i][r];
            v += __shfl_xor(v, 1, 64);
            v += __shfl_xor(v, 2, 64);
            v += __shfl_xor(v, 4, 64);
            v += __shfl_xor(v, 8, 64);
            int orow = row0 + i*16 + quad*4 + r;
            if (l16 == 0 && orow < cnt)
                atomicAdd(&s_out[idx[orow]], v);
        }
    }
}

// ------------- fused sumexp dispatch (period-4 interleave, 2048 blocks) -----
__global__ __launch_bounds__(256) void k_sumexp(
    const unsigned short* __restrict__ Xb,  const unsigned short* __restrict__ hWb,
    const unsigned short* __restrict__ h0b, const unsigned short* __restrict__ e0b,
    const unsigned short* __restrict__ h1b, const unsigned short* __restrict__ e1b,
    float* __restrict__ sH, float* __restrict__ s0, float* __restrict__ s1,
    const int* __restrict__ idx0, const int* __restrict__ idx1,
    const int* __restrict__ cnt)
{
    __shared__ __align__(16) unsigned short As[2*4096];
    __shared__ __align__(16) unsigned short Bs[2*4096];
    const int b = blockIdx.x;          // 2048 blocks: H,T1,T0,T1 repeating
    const int m4 = b & 3;
    if (m4 == 0){
        int id = b >> 2, rowb = id >> 3, split = id & 7;
        sumexp_lds<1024>(Xb, hWb, sH, 2002, rowb, split*4, split*4 + 4,
                         As, Bs, nullptr, 4096);
    } else if (m4 == 2){
        int id = b >> 2, rowb = id >> 3, split = id & 7;
        int c0 = cnt[0];
        if (rowb < ((c0 + 63) >> 6)){
            int cb0 = split*15 + min(split, 5);
            int cb1 = cb0 + 15 + (split < 5 ? 1 : 0);
            sumexp_lds<256>(h0b, e0b, s0, 8000, rowb, cb0, cb1,
                            As, Bs, idx0, c0);
        }
    } else {
        int wid = (b >> 1)*4 + (threadIdx.x >> 6);
        int rowg = wid >> 6, split = wid & 63;
        int c1 = cnt[1];
        if (rowg < ((c1 + 63) >> 6)){
            int g0 = split*39 + min(split, 21);
            int g1 = g0 + 39 + (split < 21 ? 1 : 0);
            sumexp_stream64(h1b, e1b, s1, rowg*64, g0, g1, idx1, c1);
        }
    }
}

// ---------------- combine + fused loss ---------------------------------------
__global__ __launch_bounds__(256) void k_combine(
    const unsigned short* __restrict__ Xb,   const unsigned short* __restrict__ hWb,
    const unsigned short* __restrict__ h0b,  const unsigned short* __restrict__ e0b,
    const unsigned short* __restrict__ h1b,  const unsigned short* __restrict__ e1b,
    const float* __restrict__ sH, const float* __restrict__ s0,
    const float* __restrict__ s1,
    const int* __restrict__ targets,
    const int* __restrict__ pos0, const int* __restrict__ pos1,
    float* __restrict__ lossacc, int* __restrict__ ticket,
    float* __restrict__ out)
{
    __shared__ float red4[4];
    int w = threadIdx.x >> 6, lane = threadIdx.x & 63;
    int row = blockIdx.x*4 + w;
    int t = targets[row];
    int hidx = t < 2000 ? t : (t < 10000 ? 2000 : 2001);
    int c0 = pos0[row], c1 = pos1[row];

    float dh = 0.f;
    {
        const uint4* xa = (const uint4*)(Xb  + (size_t)row*1024  + lane*16);
        const uint4* wb = (const uint4*)(hWb + (size_t)hidx*1024 + lane*16);
        #pragma unroll
        for (int p = 0; p < 2; ++p){
            uint4 xv = xa[p], wv = wb[p];
            dh += dotu(xv.x, wv.x) + dotu(xv.y, wv.y)
                + dotu(xv.z, wv.z) + dotu(xv.w, wv.w);
        }
    }
    int rel0 = min(max(t - 2000, 0), 7999);
    int rel1 = min(max(t - 10000, 0), 40256);
    float d0;
    {
        uint2 xv = *(const uint2*)(h0b + (size_t)c0*256  + lane*4);
        uint2 wv = *(const uint2*)(e0b + (size_t)rel0*256 + lane*4);
        d0 = dotu(xv.x, wv.x) + dotu(xv.y, wv.y);
    }
    float d1 = b2f(h1b[(size_t)c1*64 + lane]) * b2f(e1b[(size_t)rel1*64 + lane]);

    #pragma unroll
    for (int m = 1; m < 64; m <<= 1){
        dh += __shfl_xor(dh, m, 64);
        d0 += __shfl_xor(d0, m, 64);
        d1 += __shfl_xor(d1, m, 64);
    }
    if (lane == 0){
        float lp = dh - log2f(sH[row]);
        if (t >= 2000 && t < 10000) lp += d0 - log2f(s0[row]);
        if (t >= 10000)             lp += d1 - log2f(s1[row]);
        float val = LN2 * lp;
        out[row] = val;
        red4[w] = val;
    }
    __syncthreads();
    if (threadIdx.x == 0){
        atomicAdd(lossacc, red4[0] + red4[1] + red4[2] + red4[3]);
        __threadfence();
        int old = atomicAdd(ticket, 1);
        if (old == 1023){
            __threadfence();
            float tot = atomicAdd(lossacc, 0.0f);
            out[4096] = -tot / 4096.f;
        }
    }
}

// ---------------- host launch ----------------
extern "C" void kernel_launch(void* const* d_in, const int* in_sizes, int n_in,
                              void* d_out, int out_size, void* d_ws, size_t ws_size,
                              hipStream_t stream) {
    const float* X      = (const float*)d_in[0];
    const int*   tgt    = (const int*)  d_in[1];
    const float* headW  = (const float*)d_in[2];
    const float* emb0   = (const float*)d_in[3];
    const float* lin0   = (const float*)d_in[4];
    const float* emb1   = (const float*)d_in[5];
    const float* lin1   = (const float*)d_in[6];
    float* out = (float*)d_out;

    char* ws = (char*)d_ws;
    unsigned short* Xb  = (unsigned short*)(ws + 0);          // 8,388,608
    unsigned short* hWb = (unsigned short*)(ws + 8388608);    // 4,100,096
    unsigned short* e0b = (unsigned short*)(ws + 12488704);   // 4,096,000
    unsigned short* e1b = (unsigned short*)(ws + 16584704);   // 5,152,896
    unsigned short* l0T = (unsigned short*)(ws + 21737600);   //   524,288
    unsigned short* l1T = (unsigned short*)(ws + 22261888);   //   131,072
    unsigned short* h0b = (unsigned short*)(ws + 22392960);   // 2,097,152
    unsigned short* h1b = (unsigned short*)(ws + 24490112);   //   524,288
    float* sums         = (float*)(ws + 25014400);            // 49,152 (3x4096 f32)
    int*   cnt          = (int*)  (ws + 25063552);            // cnt0, cnt1
    int*   ticket       = (int*)  (ws + 25063560);
    float* lossacc      = (float*)(ws + 25063564);
    int*   idx0         = (int*)  (ws + 25063568);            // 16,384
    int*   idx1         = (int*)  (ws + 25079952);
    int*   pos0         = (int*)  (ws + 25096336);
    int*   pos1         = (int*)  (ws + 25112720);            // ends 25,129,104
    float* sH = sums, *s0 = sums + 4096, *s1 = sums + 8192;

    // zero sums + cnt/ticket/lossacc in one shot (49,152 + 16 bytes)
    hipMemsetAsync(ws + 25014400, 0, 49168, stream);

    k_prep<<<2048, 256, 0, stream>>>(X, headW, emb0, emb1, lin0, lin1, tgt,
                                     Xb, hWb, e0b, e1b, l0T, l1T,
                                     idx0, idx1, pos0, pos1, cnt);
    k_hgemm<<<320, 256, 0, stream>>>(Xb, l0T, h0b, l1T, h1b, idx0, idx1, cnt);
    k_sumexp<<<2048, 256, 0, stream>>>(Xb, hWb, h0b, e0b, h1b, e1b,
                                       sH, s0, s1, idx0, idx1, cnt);
    k_combine<<<1024, 256, 0, stream>>>(Xb, hWb, h0b, e0b, h1b, e1b,
                                        sH, s0, s1, tgt, pos0, pos1,
                                        lossacc, ticket, out);
}